// Round 7
// baseline (221.252 us; speedup 1.0000x reference)
//
#include <hip/hip_runtime.h>

#define N_NODES 100000
#define D_IN 32
#define H 64
#define EPS 1e-5f
#define RSTR 32     // bucket row: 32 entry slots (128B)
#define CAP 32
#define OV_CAP 32768

typedef float floatx2 __attribute__((ext_vector_type(2)));

__device__ __forceinline__ unsigned short f2bf(float f) {
    union { float f; unsigned int u; } c; c.f = f;
    unsigned int b = c.u + 0x7FFFu + ((c.u >> 16) & 1u);   // RNE
    return (unsigned short)(b >> 16);
}
__device__ __forceinline__ float bf2f(unsigned short s) {
    union { unsigned int u; float f; } c; c.u = ((unsigned int)s) << 16;
    return c.f;
}

// ================= fused: scatter + MLP (R0 structure) =================
// R15: fused left at the R0 baseline (atomic-contention, occupancy, and
// line-stride levers all falsified in R3-R6; fused sits at the random-line
// fabric ceiling). Only change: MLP epilogue writes the fp8 row as TWO
// 32B half-rows into separate 3.2MB tables (channels 0-31 / 32-63) so the
// aggregation passes can each work from an L2-resident table.
__global__ __launch_bounds__(256, 2) void fused_kernel(
    const float* __restrict__ x,
    const float* __restrict__ W1, const float* __restrict__ b1,
    const float* __restrict__ g1, const float* __restrict__ be1,
    const float* __restrict__ W2, const float* __restrict__ b2,
    const float* __restrict__ g2, const float* __restrict__ be2,
    unsigned short* __restrict__ hb,
    unsigned int* __restrict__ hb8a, unsigned int* __restrict__ hb8b,
    const int* __restrict__ ei, int* __restrict__ cnt, int* __restrict__ bkt,
    int* __restrict__ ovCnt, int2* __restrict__ ov,
    int E, int SB, int TOT)
{
    const int i = blockIdx.x;
    const int before = (int)((long long)i * SB / TOT);
    const int after  = (int)((long long)(i + 1) * SB / TOT);

    if (after > before) {
        // ---------------- scatter: 8 edges/thread ----------------
        int t = before * 256 + threadIdx.x;
        int e0 = t * 8;
        if (e0 >= E) return;

        int rows[8], cols[8], pos[8];
        if (e0 + 7 < E) {
            int4 r0 = *(const int4*)(ei + e0);
            int4 r1 = *(const int4*)(ei + e0 + 4);
            int4 c0 = *(const int4*)(ei + E + e0);
            int4 c1 = *(const int4*)(ei + E + e0 + 4);
            rows[0]=r0.x; rows[1]=r0.y; rows[2]=r0.z; rows[3]=r0.w;
            rows[4]=r1.x; rows[5]=r1.y; rows[6]=r1.z; rows[7]=r1.w;
            cols[0]=c0.x; cols[1]=c0.y; cols[2]=c0.z; cols[3]=c0.w;
            cols[4]=c1.x; cols[5]=c1.y; cols[6]=c1.z; cols[7]=c1.w;
        } else {
#pragma unroll
            for (int j = 0; j < 8; ++j) {
                int e = e0 + j;
                if (e < E) { rows[j] = ei[e]; cols[j] = ei[E + e]; }
                else rows[j] = -1;
            }
        }
#pragma unroll
        for (int j = 0; j < 8; ++j)
            if (rows[j] >= 0) pos[j] = atomicAdd(&cnt[rows[j]], 1);
#pragma unroll
        for (int j = 0; j < 8; ++j) {
            if (rows[j] < 0) continue;
            if (pos[j] < CAP) {
                __builtin_nontemporal_store(cols[j], &bkt[rows[j] * RSTR + pos[j]]);
            } else {
                int s = atomicAdd(ovCnt, 1);
                if (s < OV_CAP) ov[s] = make_int2(rows[j], cols[j]);
            }
        }
        return;
    }

    // ---------------- MLP: thread-per-node ----------------
    int gid = (i - before) * 256 + threadIdx.x;
    int node = gid < N_NODES ? gid : N_NODES - 1;

    float xr[D_IN];
    {
        const float4* xp = (const float4*)(x + (long long)node * D_IN);
#pragma unroll
        for (int i2 = 0; i2 < D_IN / 4; ++i2) {
            float4 v = xp[i2];
            xr[4*i2+0] = v.x; xr[4*i2+1] = v.y; xr[4*i2+2] = v.z; xr[4*i2+3] = v.w;
        }
    }

    float h1[H];
#pragma unroll
    for (int jb = 0; jb < H / 4; ++jb) {
        float4 b = *(const float4*)(b1 + jb * 4);
        h1[4*jb+0] = b.x; h1[4*jb+1] = b.y; h1[4*jb+2] = b.z; h1[4*jb+3] = b.w;
    }
#pragma unroll
    for (int k = 0; k < D_IN; ++k) {
        float xk = xr[k];
#pragma unroll
        for (int jb = 0; jb < H / 4; ++jb) {
            float4 w = *(const float4*)(W1 + k * H + jb * 4);
            h1[4*jb+0] += xk * w.x; h1[4*jb+1] += xk * w.y;
            h1[4*jb+2] += xk * w.z; h1[4*jb+3] += xk * w.w;
        }
    }
    {
        float s0=0,s1=0,s2=0,s3=0, q0=0,q1=0,q2=0,q3=0;
#pragma unroll
        for (int j = 0; j < H; j += 4) {
            s0 += h1[j+0]; s1 += h1[j+1]; s2 += h1[j+2]; s3 += h1[j+3];
            q0 += h1[j+0]*h1[j+0]; q1 += h1[j+1]*h1[j+1];
            q2 += h1[j+2]*h1[j+2]; q3 += h1[j+3]*h1[j+3];
        }
        float mu  = (s0+s1+s2+s3) * (1.0f / H);
        float var = (q0+q1+q2+q3) * (1.0f / H) - mu * mu;
        float rs  = rsqrtf(var + EPS);
#pragma unroll
        for (int jb = 0; jb < H / 4; ++jb) {
            float4 g = *(const float4*)(g1 + jb * 4);
            float4 be = *(const float4*)(be1 + jb * 4);
            h1[4*jb+0] = fmaxf((h1[4*jb+0]-mu)*rs*g.x + be.x, 0.0f);
            h1[4*jb+1] = fmaxf((h1[4*jb+1]-mu)*rs*g.y + be.y, 0.0f);
            h1[4*jb+2] = fmaxf((h1[4*jb+2]-mu)*rs*g.z + be.z, 0.0f);
            h1[4*jb+3] = fmaxf((h1[4*jb+3]-mu)*rs*g.w + be.w, 0.0f);
        }
    }

    float h2[H];
#pragma unroll
    for (int jb = 0; jb < H / 4; ++jb) {
        float4 b = *(const float4*)(b2 + jb * 4);
        h2[4*jb+0] = b.x; h2[4*jb+1] = b.y; h2[4*jb+2] = b.z; h2[4*jb+3] = b.w;
    }
#pragma unroll
    for (int k = 0; k < H; ++k) {
        float hk = h1[k];
#pragma unroll
        for (int jb = 0; jb < H / 4; ++jb) {
            float4 w = *(const float4*)(W2 + k * H + jb * 4);
            h2[4*jb+0] += hk * w.x; h2[4*jb+1] += hk * w.y;
            h2[4*jb+2] += hk * w.z; h2[4*jb+3] += hk * w.w;
        }
    }
    {
        float s0=0,s1=0,s2=0,s3=0, q0=0,q1=0,q2=0,q3=0;
#pragma unroll
        for (int j = 0; j < H; j += 4) {
            s0 += h2[j+0]; s1 += h2[j+1]; s2 += h2[j+2]; s3 += h2[j+3];
            q0 += h2[j+0]*h2[j+0]; q1 += h2[j+1]*h2[j+1];
            q2 += h2[j+2]*h2[j+2]; q3 += h2[j+3]*h2[j+3];
        }
        float mu  = (s0+s1+s2+s3) * (1.0f / H);
        float var = (q0+q1+q2+q3) * (1.0f / H) - mu * mu;
        float rs  = rsqrtf(var + EPS);

        unsigned short* hp = hb + (long long)node * H;
        unsigned int w8[H / 4];
#pragma unroll
        for (int jb = 0; jb < H / 4; ++jb) {
            float4 g = *(const float4*)(g2 + jb * 4);
            float4 be = *(const float4*)(be2 + jb * 4);
            float4 v;
            v.x = fmaxf((h2[4*jb+0]-mu)*rs*g.x + be.x, 0.0f);
            v.y = fmaxf((h2[4*jb+1]-mu)*rs*g.y + be.y, 0.0f);
            v.z = fmaxf((h2[4*jb+2]-mu)*rs*g.z + be.z, 0.0f);
            v.w = fmaxf((h2[4*jb+3]-mu)*rs*g.w + be.w, 0.0f);
            ushort4 u;
            u.x = f2bf(v.x); u.y = f2bf(v.y); u.z = f2bf(v.z); u.w = f2bf(v.w);
            *(ushort4*)(hp + 4*jb) = u;
            int lo = __builtin_amdgcn_cvt_pk_fp8_f32(v.x, v.y, 0, false);
            w8[jb] = (unsigned int)__builtin_amdgcn_cvt_pk_fp8_f32(v.z, v.w, lo, true);
        }
        // split fp8 row: channels 0-31 -> hb8a (32B), 32-63 -> hb8b (32B)
        unsigned int* pa = hb8a + (long long)node * 8;
        unsigned int* pb = hb8b + (long long)node * 8;
        *(uint4*)(pa)     = make_uint4(w8[0],  w8[1],  w8[2],  w8[3]);
        *(uint4*)(pa + 4) = make_uint4(w8[4],  w8[5],  w8[6],  w8[7]);
        *(uint4*)(pb)     = make_uint4(w8[8],  w8[9],  w8[10], w8[11]);
        *(uint4*)(pb + 4) = make_uint4(w8[12], w8[13], w8[14], w8[15]);
    }
}

// ================= pull aggregation: channel-split, L2-resident table =================
// R15 theory: aggr's 100us = 1.25M random 64B gathers from a 6.4MB table
// that does NOT fit the 4MB per-XCD L2 -> every gather is an L3/fabric
// round-trip at the ~0.8TB/s random-line ceiling (same wall as fused's
// scatter, observed R0-R6). Fix: two sequential passes, each gathering 32B
// rows from a 3.2MB half-table that fits in L2 on every XCD. Lane remap:
// 8 nodes/wave (sub=t>>3), 8 lanes/row (c=t&7, one uint = 4 fp8 channels).
// Same per-channel summation order -> bit-identical output. Two LAUNCHES,
// not one interleaved grid (interleaving would cache both tables per XCD
// = 6.4MB again).
__global__ __launch_bounds__(256, 2) void aggr_half_kernel(
    const int* __restrict__ cnt, const int* __restrict__ bkt,
    const unsigned short* __restrict__ hb,
    const unsigned int* __restrict__ h8,   // 3.2MB half-table, 8 uints/row
    float* __restrict__ out,
    const int* __restrict__ ovCnt, const int2* __restrict__ ov,
    int chanBase)                          // 0 or 32 (shorts/floats offset = chanBase)
{
    const int t    = threadIdx.x & 63;
    const int sub  = t >> 3;                       // 8 nodes per wave
    const int c    = t & 7;                        // uint within 32B half-row
    const int wave = blockIdx.x * 4 + (threadIdx.x >> 6);
    const int node = wave * 8 + sub;               // grid exact: 3125*32 = 100000

    int m = cnt[node];
    if (m > CAP) m = CAP;
    const int base = node * RSTR;
    const int co = chanBase + c * 4;               // channel offset (shorts/floats)

    float a0 = 0.f, a1 = 0.f, a2 = 0.f, a3 = 0.f;
#pragma unroll
    for (int j0 = 0; j0 < CAP; j0 += 16) {
        int cc[16];
#pragma unroll
        for (int i = 0; i < 16; ++i)               // broadcast loads (8 lanes/addr)
            cc[i] = bkt[base + j0 + i];
        unsigned int vv[16];
#pragma unroll
        for (int i = 0; i < 16; ++i)               // independent 4B gathers (32B/row, L2-hit)
            if (j0 + i < m) vv[i] = h8[(cc[i] << 3) + c];
#pragma unroll
        for (int i = 0; i < 16; ++i) {
            if (j0 + i < m) {
                floatx2 p0 = __builtin_amdgcn_cvt_pk_f32_fp8(vv[i], false);
                floatx2 p1 = __builtin_amdgcn_cvt_pk_f32_fp8(vv[i], true);
                a0 += p0.x; a1 += p0.y; a2 += p1.x; a3 += p1.y;
            }
        }
    }

    // self term (bf16 precision, sequential access)
    {
        uint2 sv = *(const uint2*)(hb + ((long long)node << 6) + co);
        a0 += bf2f((unsigned short)(sv.x & 0xFFFFu));
        a1 += bf2f((unsigned short)(sv.x >> 16));
        a2 += bf2f((unsigned short)(sv.y & 0xFFFFu));
        a3 += bf2f((unsigned short)(sv.y >> 16));
    }

    // exact overflow drain (normally 0 entries)
    int nov = *ovCnt; if (nov > OV_CAP) nov = OV_CAP;
    for (int i = 0; i < nov; ++i) {
        int2 rc = ov[i];
        if (rc.x == node) {
            uint2 vv = *(const uint2*)(hb + ((long long)rc.y << 6) + co);
            a0 += bf2f((unsigned short)(vv.x & 0xFFFFu));
            a1 += bf2f((unsigned short)(vv.x >> 16));
            a2 += bf2f((unsigned short)(vv.y & 0xFFFFu));
            a3 += bf2f((unsigned short)(vv.y >> 16));
        }
    }

    *(float4*)(out + ((long long)node << 6) + co) = make_float4(a0, a1, a2, a3);
}

extern "C" void kernel_launch(void* const* d_in, const int* in_sizes, int n_in,
                              void* d_out, int out_size, void* d_ws, size_t ws_size,
                              hipStream_t stream)
{
    const float* x   = (const float*)d_in[0];
    const int*   ei  = (const int*)d_in[1];
    const float* W1  = (const float*)d_in[2];
    const float* b1  = (const float*)d_in[3];
    const float* g1  = (const float*)d_in[4];
    const float* be1 = (const float*)d_in[5];
    const float* W2  = (const float*)d_in[6];
    const float* b2  = (const float*)d_in[7];
    const float* g2  = (const float*)d_in[8];
    const float* be2 = (const float*)d_in[9];

    float* out = (float*)d_out;

    // workspace layout (~32.7 MB)
    char* ws = (char*)d_ws;
    unsigned short* hb    = (unsigned short*)ws;             // 12,800,000 B
    unsigned int*   hb8a  = (unsigned int*)(ws + 12800000);  //  3,200,000 B (ch 0-31)
    unsigned int*   hb8b  = (unsigned int*)(ws + 16000000);  //  3,200,000 B (ch 32-63)
    int*            cnt   = (int*)(ws + 19200000);           //    400,000 B (packed)
    int*            ovCnt = (int*)(ws + 19600000);           //         64 B
    int2*           ov    = (int2*)(ws + 19600064);          //    262,144 B
    int*            bkt   = (int*)(ws + 19862208);           // 12,800,000 B (nt-written, never zeroed)

    const int E = in_sizes[1] / 2;

    (void)hipMemsetAsync(cnt, 0, 400064, stream);            // cnt + ovCnt

    const int SB = ((E + 7) / 8 + 255) / 256;           // 611 scatter blocks
    const int MB = (N_NODES + 255) / 256;               // 391 mlp blocks
    fused_kernel<<<SB + MB, 256, 0, stream>>>(
        x, W1, b1, g1, be1, W2, b2, g2, be2, hb, hb8a, hb8b,
        ei, cnt, bkt, ovCnt, ov, E, SB, SB + MB);

    aggr_half_kernel<<<N_NODES / 32, 256, 0, stream>>>(cnt, bkt, hb, hb8a, out, ovCnt, ov, 0);
    aggr_half_kernel<<<N_NODES / 32, 256, 0, stream>>>(cnt, bkt, hb, hb8b, out, ovCnt, ov, 32);
}

// Round 8
// 205.888 us; speedup vs baseline: 1.0746x; 1.0746x over previous
//
#include <hip/hip_runtime.h>

#define N_NODES 100000
#define D_IN 32
#define H 64
#define EPS 1e-5f
#define RSTR 32     // bucket row: 32 entry slots (128B)
#define CAP 32
#define OV_CAP 32768

typedef float floatx2 __attribute__((ext_vector_type(2)));

__device__ __forceinline__ unsigned short f2bf(float f) {
    union { float f; unsigned int u; } c; c.f = f;
    unsigned int b = c.u + 0x7FFFu + ((c.u >> 16) & 1u);   // RNE
    return (unsigned short)(b >> 16);
}
__device__ __forceinline__ float bf2f(unsigned short s) {
    union { unsigned int u; float f; } c; c.u = ((unsigned int)s) << 16;
    return c.f;
}

// ================= fused: scatter + MLP (exact R0 baseline — control) =================
__global__ __launch_bounds__(256, 2) void fused_kernel(
    const float* __restrict__ x,
    const float* __restrict__ W1, const float* __restrict__ b1,
    const float* __restrict__ g1, const float* __restrict__ be1,
    const float* __restrict__ W2, const float* __restrict__ b2,
    const float* __restrict__ g2, const float* __restrict__ be2,
    unsigned short* __restrict__ hb, unsigned char* __restrict__ hb8,
    const int* __restrict__ ei, int* __restrict__ cnt, int* __restrict__ bkt,
    int* __restrict__ ovCnt, int2* __restrict__ ov,
    int E, int SB, int TOT)
{
    const int i = blockIdx.x;
    const int before = (int)((long long)i * SB / TOT);
    const int after  = (int)((long long)(i + 1) * SB / TOT);

    if (after > before) {
        // ---------------- scatter: 8 edges/thread ----------------
        int t = before * 256 + threadIdx.x;
        int e0 = t * 8;
        if (e0 >= E) return;

        int rows[8], cols[8], pos[8];
        if (e0 + 7 < E) {
            int4 r0 = *(const int4*)(ei + e0);
            int4 r1 = *(const int4*)(ei + e0 + 4);
            int4 c0 = *(const int4*)(ei + E + e0);
            int4 c1 = *(const int4*)(ei + E + e0 + 4);
            rows[0]=r0.x; rows[1]=r0.y; rows[2]=r0.z; rows[3]=r0.w;
            rows[4]=r1.x; rows[5]=r1.y; rows[6]=r1.z; rows[7]=r1.w;
            cols[0]=c0.x; cols[1]=c0.y; cols[2]=c0.z; cols[3]=c0.w;
            cols[4]=c1.x; cols[5]=c1.y; cols[6]=c1.z; cols[7]=c1.w;
        } else {
#pragma unroll
            for (int j = 0; j < 8; ++j) {
                int e = e0 + j;
                if (e < E) { rows[j] = ei[e]; cols[j] = ei[E + e]; }
                else rows[j] = -1;
            }
        }
#pragma unroll
        for (int j = 0; j < 8; ++j)
            if (rows[j] >= 0) pos[j] = atomicAdd(&cnt[rows[j]], 1);
#pragma unroll
        for (int j = 0; j < 8; ++j) {
            if (rows[j] < 0) continue;
            if (pos[j] < CAP) {
                __builtin_nontemporal_store(cols[j], &bkt[rows[j] * RSTR + pos[j]]);
            } else {
                int s = atomicAdd(ovCnt, 1);
                if (s < OV_CAP) ov[s] = make_int2(rows[j], cols[j]);
            }
        }
        return;
    }

    // ---------------- MLP: thread-per-node ----------------
    int gid = (i - before) * 256 + threadIdx.x;
    int node = gid < N_NODES ? gid : N_NODES - 1;

    float xr[D_IN];
    {
        const float4* xp = (const float4*)(x + (long long)node * D_IN);
#pragma unroll
        for (int i2 = 0; i2 < D_IN / 4; ++i2) {
            float4 v = xp[i2];
            xr[4*i2+0] = v.x; xr[4*i2+1] = v.y; xr[4*i2+2] = v.z; xr[4*i2+3] = v.w;
        }
    }

    float h1[H];
#pragma unroll
    for (int jb = 0; jb < H / 4; ++jb) {
        float4 b = *(const float4*)(b1 + jb * 4);
        h1[4*jb+0] = b.x; h1[4*jb+1] = b.y; h1[4*jb+2] = b.z; h1[4*jb+3] = b.w;
    }
#pragma unroll
    for (int k = 0; k < D_IN; ++k) {
        float xk = xr[k];
#pragma unroll
        for (int jb = 0; jb < H / 4; ++jb) {
            float4 w = *(const float4*)(W1 + k * H + jb * 4);
            h1[4*jb+0] += xk * w.x; h1[4*jb+1] += xk * w.y;
            h1[4*jb+2] += xk * w.z; h1[4*jb+3] += xk * w.w;
        }
    }
    {
        float s0=0,s1=0,s2=0,s3=0, q0=0,q1=0,q2=0,q3=0;
#pragma unroll
        for (int j = 0; j < H; j += 4) {
            s0 += h1[j+0]; s1 += h1[j+1]; s2 += h1[j+2]; s3 += h1[j+3];
            q0 += h1[j+0]*h1[j+0]; q1 += h1[j+1]*h1[j+1];
            q2 += h1[j+2]*h1[j+2]; q3 += h1[j+3]*h1[j+3];
        }
        float mu  = (s0+s1+s2+s3) * (1.0f / H);
        float var = (q0+q1+q2+q3) * (1.0f / H) - mu * mu;
        float rs  = rsqrtf(var + EPS);
#pragma unroll
        for (int jb = 0; jb < H / 4; ++jb) {
            float4 g = *(const float4*)(g1 + jb * 4);
            float4 be = *(const float4*)(be1 + jb * 4);
            h1[4*jb+0] = fmaxf((h1[4*jb+0]-mu)*rs*g.x + be.x, 0.0f);
            h1[4*jb+1] = fmaxf((h1[4*jb+1]-mu)*rs*g.y + be.y, 0.0f);
            h1[4*jb+2] = fmaxf((h1[4*jb+2]-mu)*rs*g.z + be.z, 0.0f);
            h1[4*jb+3] = fmaxf((h1[4*jb+3]-mu)*rs*g.w + be.w, 0.0f);
        }
    }

    float h2[H];
#pragma unroll
    for (int jb = 0; jb < H / 4; ++jb) {
        float4 b = *(const float4*)(b2 + jb * 4);
        h2[4*jb+0] = b.x; h2[4*jb+1] = b.y; h2[4*jb+2] = b.z; h2[4*jb+3] = b.w;
    }
#pragma unroll
    for (int k = 0; k < H; ++k) {
        float hk = h1[k];
#pragma unroll
        for (int jb = 0; jb < H / 4; ++jb) {
            float4 w = *(const float4*)(W2 + k * H + jb * 4);
            h2[4*jb+0] += hk * w.x; h2[4*jb+1] += hk * w.y;
            h2[4*jb+2] += hk * w.z; h2[4*jb+3] += hk * w.w;
        }
    }
    {
        float s0=0,s1=0,s2=0,s3=0, q0=0,q1=0,q2=0,q3=0;
#pragma unroll
        for (int j = 0; j < H; j += 4) {
            s0 += h2[j+0]; s1 += h2[j+1]; s2 += h2[j+2]; s3 += h2[j+3];
            q0 += h2[j+0]*h2[j+0]; q1 += h2[j+1]*h2[j+1];
            q2 += h2[j+2]*h2[j+2]; q3 += h2[j+3]*h2[j+3];
        }
        float mu  = (s0+s1+s2+s3) * (1.0f / H);
        float var = (q0+q1+q2+q3) * (1.0f / H) - mu * mu;
        float rs  = rsqrtf(var + EPS);

        unsigned short* hp = hb + (long long)node * H;
        unsigned int w8[H / 4];
#pragma unroll
        for (int jb = 0; jb < H / 4; ++jb) {
            float4 g = *(const float4*)(g2 + jb * 4);
            float4 be = *(const float4*)(be2 + jb * 4);
            float4 v;
            v.x = fmaxf((h2[4*jb+0]-mu)*rs*g.x + be.x, 0.0f);
            v.y = fmaxf((h2[4*jb+1]-mu)*rs*g.y + be.y, 0.0f);
            v.z = fmaxf((h2[4*jb+2]-mu)*rs*g.z + be.z, 0.0f);
            v.w = fmaxf((h2[4*jb+3]-mu)*rs*g.w + be.w, 0.0f);
            ushort4 u;
            u.x = f2bf(v.x); u.y = f2bf(v.y); u.z = f2bf(v.z); u.w = f2bf(v.w);
            *(ushort4*)(hp + 4*jb) = u;
            int lo = __builtin_amdgcn_cvt_pk_fp8_f32(v.x, v.y, 0, false);
            w8[jb] = (unsigned int)__builtin_amdgcn_cvt_pk_fp8_f32(v.z, v.w, lo, true);
        }
        unsigned int* hp8 = (unsigned int*)(hb8 + (long long)node * H);
#pragma unroll
        for (int q = 0; q < H / 16; ++q)
            *(uint4*)(hp8 + q * 4) = make_uint4(w8[4*q+0], w8[4*q+1], w8[4*q+2], w8[4*q+3]);
    }
}

// ================= pull aggregation: dwordx4 gathers, 4x fewer VMEM insts =================
// R16 theory: R0 vs R7 showed aggr time tracks per-lane VMEM request count
// (800K wave-insts both ways -> same time, despite 2x line-touches and full
// L2 residency in R7). So cut instructions: wave = 4 nodes x (quad q, group
// g); each lane loads 8 edge ids via 2x int4, then 8x uint4 gathers (16B =
// full row quad). 64 -> ~11 VMEM insts/wave for identical bytes. Per-lane
// 16-channel accumulate; shfl_xor(4,8) butterfly over the 4 edge-groups;
// lane (q,g) owns channels 16q+4g..+3 for self/overflow/store (coalesced).
__global__ __launch_bounds__(256, 2) void aggr_kernel(
    const int* __restrict__ cnt, const int* __restrict__ bkt,
    const unsigned short* __restrict__ hb, const unsigned char* __restrict__ hb8,
    float* __restrict__ out,
    const int* __restrict__ ovCnt, const int2* __restrict__ ov)
{
    const int t    = threadIdx.x & 63;
    const int sub  = t >> 4;                       // 4 nodes/wave
    const int l    = t & 15;
    const int q    = l & 3;                        // 16B quad within 64B row
    const int g    = l >> 2;                       // edge-group: 8 contiguous edges
    const int wave = blockIdx.x * 4 + (threadIdx.x >> 6);
    const int node = wave * 4 + sub;               // grid exact: 6250*16 = 100000

    int m = cnt[node];
    if (m > CAP) m = CAP;
    const int base = node * RSTR;

    // 2 VMEM: this lane's 8 contiguous edge indices [g*8, g*8+8)
    int4 ea = *(const int4*)(bkt + base + g * 8);
    int4 eb = *(const int4*)(bkt + base + g * 8 + 4);
    int ed[8] = { ea.x, ea.y, ea.z, ea.w, eb.x, eb.y, eb.z, eb.w };

    const uint4* h84 = (const uint4*)hb8;          // row = 4 uint4 (64B)
    const int e0 = g * 8;

    float s[16];
#pragma unroll
    for (int j = 0; j < 16; ++j) s[j] = 0.f;

    // 8 VMEM: one 16B gather per edge (quad q of that edge's row)
    uint4 vv[8];
#pragma unroll
    for (int k = 0; k < 8; ++k)
        if (e0 + k < m) vv[k] = h84[(ed[k] << 2) + q];

#pragma unroll
    for (int k = 0; k < 8; ++k) {
        if (e0 + k < m) {
            unsigned int w[4] = { vv[k].x, vv[k].y, vv[k].z, vv[k].w };
#pragma unroll
            for (int u = 0; u < 4; ++u) {
                floatx2 p0 = __builtin_amdgcn_cvt_pk_f32_fp8(w[u], false);
                floatx2 p1 = __builtin_amdgcn_cvt_pk_f32_fp8(w[u], true);
                s[4*u+0] += p0.x; s[4*u+1] += p0.y;
                s[4*u+2] += p1.x; s[4*u+3] += p1.y;
            }
        }
    }

    // butterfly over the 4 edge-groups (lanes differing in t bits 2-3)
#pragma unroll
    for (int j = 0; j < 16; ++j) {
        s[j] += __shfl_xor(s[j], 4, 64);
        s[j] += __shfl_xor(s[j], 8, 64);
    }

    // this lane owns channels co..co+3
    const int co = q * 16 + g * 4;
    float a0 = s[g*4+0], a1 = s[g*4+1], a2 = s[g*4+2], a3 = s[g*4+3];

    // self term (bf16 precision, sequential access)
    {
        uint2 sv = *(const uint2*)(hb + ((long long)node << 6) + co);
        a0 += bf2f((unsigned short)(sv.x & 0xFFFFu));
        a1 += bf2f((unsigned short)(sv.x >> 16));
        a2 += bf2f((unsigned short)(sv.y & 0xFFFFu));
        a3 += bf2f((unsigned short)(sv.y >> 16));
    }

    // exact overflow drain (normally 0 entries)
    int nov = *ovCnt; if (nov > OV_CAP) nov = OV_CAP;
    for (int i = 0; i < nov; ++i) {
        int2 rc = ov[i];
        if (rc.x == node) {
            uint2 vvо = *(const uint2*)(hb + ((long long)rc.y << 6) + co);
            a0 += bf2f((unsigned short)(vvо.x & 0xFFFFu));
            a1 += bf2f((unsigned short)(vvо.x >> 16));
            a2 += bf2f((unsigned short)(vvо.y & 0xFFFFu));
            a3 += bf2f((unsigned short)(vvо.y >> 16));
        }
    }

    *(float4*)(out + ((long long)node << 6) + co) = make_float4(a0, a1, a2, a3);
}

extern "C" void kernel_launch(void* const* d_in, const int* in_sizes, int n_in,
                              void* d_out, int out_size, void* d_ws, size_t ws_size,
                              hipStream_t stream)
{
    const float* x   = (const float*)d_in[0];
    const int*   ei  = (const int*)d_in[1];
    const float* W1  = (const float*)d_in[2];
    const float* b1  = (const float*)d_in[3];
    const float* g1  = (const float*)d_in[4];
    const float* be1 = (const float*)d_in[5];
    const float* W2  = (const float*)d_in[6];
    const float* b2  = (const float*)d_in[7];
    const float* g2  = (const float*)d_in[8];
    const float* be2 = (const float*)d_in[9];

    float* out = (float*)d_out;

    // workspace layout (~32.7 MB)
    char* ws = (char*)d_ws;
    unsigned short* hb    = (unsigned short*)ws;        // 12,800,000 B
    unsigned char*  hb8   = (unsigned char*)(ws + 12800000); // 6,400,000 B
    int*            cnt   = (int*)(ws + 19200000);      //    400,000 B
    int*            ovCnt = (int*)(ws + 19600000);      //         64 B
    int2*           ov    = (int2*)(ws + 19600064);     //    262,144 B
    int*            bkt   = (int*)(ws + 19862208);      // 12,800,000 B (nt-written, never zeroed)

    const int E = in_sizes[1] / 2;

    (void)hipMemsetAsync(cnt, 0, 400064, stream);       // cnt + ovCnt

    const int SB = ((E + 7) / 8 + 255) / 256;           // 611 scatter blocks
    const int MB = (N_NODES + 255) / 256;               // 391 mlp blocks
    fused_kernel<<<SB + MB, 256, 0, stream>>>(
        x, W1, b1, g1, be1, W2, b2, g2, be2, hb, hb8,
        ei, cnt, bkt, ovCnt, ov, E, SB, SB + MB);

    aggr_kernel<<<N_NODES / 16, 256, 0, stream>>>(cnt, bkt, hb, hb8, out, ovCnt, ov);
}